// Round 4
// baseline (173.247 us; speedup 1.0000x reference)
//
#include <hip/hip_runtime.h>
#include <hip/hip_bf16.h>

// Problem constants
#define B_    2048
#define NC_   32
#define H1_   64
#define H2_   32
#define CLS_  10
#define M_    496
#define EPS_  1e-5f

// m -> (i0,i1): lexicographic pair from combinations(range(32),2).
// Computed on device (wave-uniform) -> immune to harness index dtype.
__device__ __forceinline__ void pair_of_m(int m, int& i0, int& i1) {
    int a = 0, rem = m;
    while (rem >= (NC_ - 1 - a)) { rem -= (NC_ - 1 - a); ++a; }
    i0 = a; i1 = a + 1 + rem;
}

// ---------------- primary main kernel ----------------
// grid = (M, B/256), block = 256. One thread = one (batch b, pair m).
__global__ __launch_bounds__(256) void k_main(
    const float* __restrict__ x,
    const float* __restrict__ W1, const float* __restrict__ b1,
    const float* __restrict__ g1, const float* __restrict__ be1,
    const float* __restrict__ m1, const float* __restrict__ v1,
    const float* __restrict__ W2, const float* __restrict__ b2p,
    const float* __restrict__ g2, const float* __restrict__ be2,
    const float* __restrict__ m2, const float* __restrict__ v2,
    const float* __restrict__ W3, const float* __restrict__ b3,
    float* __restrict__ obuf)
{
    __shared__ float w1a[H1_], w1b[H1_], c1[H1_];
    __shared__ float s2s[H2_], c2s[H2_], w3s[H2_];

    const int m   = blockIdx.x;
    const int tid = threadIdx.x;

    if (tid < H1_) {                       // layer-1 fold: one thread per o
        int j = m * H1_ + tid;
        float s = g1[j] * rsqrtf(v1[j] + EPS_);
        w1a[tid] = s * W1[2 * j];
        w1b[tid] = s * W1[2 * j + 1];
        c1[tid]  = fmaf(s, b1[j] - m1[j], be1[j]);
    } else if (tid < H1_ + H2_) {          // layer-2 fold
        int o = tid - H1_;
        int j = m * H2_ + o;
        float s = g2[j] * rsqrtf(v2[j] + EPS_);
        s2s[o] = s;
        c2s[o] = fmaf(s, b2p[j] - m2[j], be2[j]);
        w3s[o] = W3[j];
    }
    __syncthreads();

    int i0, i1;
    pair_of_m(m, i0, i1);
    const int b  = blockIdx.y * 256 + tid;
    const float x0 = x[b * NC_ + i0];
    const float x1 = x[b * NC_ + i1];

    float h1[H1_];
#pragma unroll
    for (int o = 0; o < H1_; ++o)
        h1[o] = fmaxf(fmaf(x0, w1a[o], fmaf(x1, w1b[o], c1[o])), 0.f);

    const float* __restrict__ W2m = W2 + m * (H2_ * H1_);
    float acc3 = b3[m];
#pragma unroll 2
    for (int o = 0; o < H2_; ++o) {
        const float* __restrict__ r = W2m + o * H1_;
        float d0 = 0.f, d1 = 0.f, d2 = 0.f, d3 = 0.f;
#pragma unroll
        for (int i = 0; i < H1_; i += 4) {
            d0 = fmaf(h1[i],     r[i],     d0);
            d1 = fmaf(h1[i + 1], r[i + 1], d1);
            d2 = fmaf(h1[i + 2], r[i + 2], d2);
            d3 = fmaf(h1[i + 3], r[i + 3], d3);
        }
        float h2 = fmaxf(fmaf(s2s[o], (d0 + d1) + (d2 + d3), c2s[o]), 0.f);
        acc3 = fmaf(h2, w3s[o], acc3);
    }
    obuf[b * M_ + m] = acc3;   // b-major for k_out float4 reads
}

// ---------------- output projection (f32 output!) ----------------
__global__ __launch_bounds__(256) void k_out(
    const float* __restrict__ obuf, const float* __restrict__ Wout,
    const float* __restrict__ bout, float* __restrict__ out)
{
    int t = blockIdx.x * 256 + threadIdx.x;   // grid covers exactly B*CLS
    int c = t >> 11;               // /2048
    int b = t & (B_ - 1);
    const float* __restrict__ op = obuf + b * M_;
    const float* __restrict__ wp = Wout + c * M_;
    float acc = bout[c];
#pragma unroll 4
    for (int m4 = 0; m4 < M_; m4 += 4) {
        float4 o4 = *(const float4*)(op + m4);
        float4 w4 = *(const float4*)(wp + m4);
        acc = fmaf(o4.x, w4.x, fmaf(o4.y, w4.y, fmaf(o4.z, w4.z, fmaf(o4.w, w4.w, acc))));
    }
    out[b * CLS_ + c] = acc;
}

// ---------------- workspace-free fallback: fully fused ----------------
__global__ __launch_bounds__(256) void k_fused(
    const float* __restrict__ x,
    const float* __restrict__ W1, const float* __restrict__ b1,
    const float* __restrict__ g1, const float* __restrict__ be1,
    const float* __restrict__ m1, const float* __restrict__ v1,
    const float* __restrict__ W2, const float* __restrict__ b2p,
    const float* __restrict__ g2, const float* __restrict__ be2,
    const float* __restrict__ m2, const float* __restrict__ v2,
    const float* __restrict__ W3, const float* __restrict__ b3,
    const float* __restrict__ Wout, const float* __restrict__ bout,
    float* __restrict__ out)
{
    __shared__ float red[256 * CLS_];
    const int tid = threadIdx.x;
    const int bl  = tid & 7;        // batch lane within block
    const int mg  = tid >> 3;       // m-group 0..31
    const int b   = blockIdx.x * 8 + bl;

    float acc[CLS_];
#pragma unroll
    for (int c = 0; c < CLS_; ++c) acc[c] = 0.f;

    for (int m = mg; m < M_; m += 32) {
        int i0, i1;
        pair_of_m(m, i0, i1);
        const float x0 = x[b * NC_ + i0];
        const float x1 = x[b * NC_ + i1];

        float h1[H1_];
#pragma unroll
        for (int o = 0; o < H1_; ++o) {
            int j = m * H1_ + o;
            float s = g1[j] * rsqrtf(v1[j] + EPS_);
            float pre = fmaf(x0, s * W1[2 * j],
                        fmaf(x1, s * W1[2 * j + 1],
                             fmaf(s, b1[j] - m1[j], be1[j])));
            h1[o] = fmaxf(pre, 0.f);
        }
        float acc3 = b3[m];
#pragma unroll 2
        for (int o = 0; o < H2_; ++o) {
            int j = m * H2_ + o;
            const float* __restrict__ r = W2 + j * H1_;
            float d = 0.f;
#pragma unroll
            for (int i = 0; i < H1_; ++i) d = fmaf(h1[i], r[i], d);
            float s = g2[j] * rsqrtf(v2[j] + EPS_);
            float h2 = fmaxf(fmaf(s, d + b2p[j] - m2[j], be2[j]), 0.f);
            acc3 = fmaf(h2, W3[j], acc3);
        }
#pragma unroll
        for (int c = 0; c < CLS_; ++c)
            acc[c] = fmaf(acc3, Wout[c * M_ + m], acc[c]);
    }

#pragma unroll
    for (int c = 0; c < CLS_; ++c) red[tid * CLS_ + c] = acc[c];
    __syncthreads();

    if (mg == 0) {                  // 8 threads finish 8 batches
#pragma unroll
        for (int c = 0; c < CLS_; ++c) {
            float s = bout[c];
            for (int g = 0; g < 32; ++g)
                s += red[(g * 8 + bl) * CLS_ + c];
            out[b * CLS_ + c] = s;
        }
    }
}

// ---------------- launch ----------------
extern "C" void kernel_launch(void* const* d_in, const int* in_sizes, int n_in,
                              void* d_out, int out_size, void* d_ws, size_t ws_size,
                              hipStream_t stream)
{
    const float* x    = (const float*)d_in[0];
    // d_in[1] (pair_idx) unused: recomputed on device (dtype-immune).
    const float* W1   = (const float*)d_in[2];
    const float* b1   = (const float*)d_in[3];
    const float* g1   = (const float*)d_in[4];
    const float* be1  = (const float*)d_in[5];
    const float* m1   = (const float*)d_in[6];
    const float* v1   = (const float*)d_in[7];
    const float* W2   = (const float*)d_in[8];
    const float* b2p  = (const float*)d_in[9];
    const float* g2   = (const float*)d_in[10];
    const float* be2  = (const float*)d_in[11];
    const float* m2   = (const float*)d_in[12];
    const float* v2   = (const float*)d_in[13];
    const float* W3   = (const float*)d_in[14];
    const float* b3   = (const float*)d_in[15];
    const float* Wout = (const float*)d_in[16];
    const float* bout = (const float*)d_in[17];
    float* out = (float*)d_out;                 // reference output dtype = f32
    float* obuf = (float*)d_ws;

    if (ws_size >= (size_t)B_ * M_ * sizeof(float)) {
        k_main<<<dim3(M_, B_ / 256), 256, 0, stream>>>(
            x, W1, b1, g1, be1, m1, v1,
            W2, b2p, g2, be2, m2, v2, W3, b3, obuf);
        k_out<<<(B_ * CLS_) / 256, 256, 0, stream>>>(obuf, Wout, bout, out);
    } else {
        k_fused<<<B_ / 8, 256, 0, stream>>>(
            x, W1, b1, g1, be1, m1, v1,
            W2, b2p, g2, be2, m2, v2, W3, b3, Wout, bout, out);
    }
}

// Round 5
// 151.483 us; speedup vs baseline: 1.1437x; 1.1437x over previous
//
#include <hip/hip_runtime.h>
#include <hip/hip_bf16.h>

// Problem constants
#define B_    2048
#define NC_   32
#define H1_   64
#define H2_   32
#define CLS_  10
#define M_    496
#define EPS_  1e-5f

typedef __attribute__((ext_vector_type(8))) short bf16x8;  // 8 bf16 (4 VGPRs)
typedef __attribute__((ext_vector_type(4))) float f32x4;   // MFMA C/D

// float -> bf16 (RNE), bit-exact and API-independent
__device__ __forceinline__ short f2bf(float f) {
    unsigned u = __float_as_uint(f);
    u = (u + 0x7FFFu + ((u >> 16) & 1u)) >> 16;
    return (short)u;
}

// m -> (i0,i1): lexicographic pair from combinations(range(32),2).
__device__ __forceinline__ void pair_of_m(int m, int& i0, int& i1) {
    int a = 0, rem = m;
    while (rem >= (NC_ - 1 - a)) { rem -= (NC_ - 1 - a); ++a; }
    i0 = a; i1 = a + 1 + rem;
}

// ---------------- MFMA main kernel ----------------
// grid = (M_, 8), block = 256 (4 waves). One block: one m, 256 batches.
// Wave w handles 4 b-tiles of 16. Layer-2 GEMM via mfma_f32_16x16x32_bf16:
//   A[b][k]=h1 (reg-built in A-frag layout), B[k][n]=W2[n][k] (already B^T form).
__global__ __launch_bounds__(256) void k_mfma(
    const float* __restrict__ x,
    const float* __restrict__ W1, const float* __restrict__ b1,
    const float* __restrict__ g1, const float* __restrict__ be1,
    const float* __restrict__ m1, const float* __restrict__ v1,
    const float* __restrict__ W2, const float* __restrict__ b2p,
    const float* __restrict__ g2, const float* __restrict__ be2,
    const float* __restrict__ m2, const float* __restrict__ v2,
    const float* __restrict__ W3, const float* __restrict__ b3,
    float* __restrict__ obuf)
{
    __shared__ float4 fold1[H1_];                 // (w1a, w1b, c1, -)
    __shared__ float s2s[H2_], c2s[H2_], w3s[H2_];

    const int m   = blockIdx.x;
    const int tid = threadIdx.x;

    if (tid < H1_) {                              // layer-1 BN fold
        int j = m * H1_ + tid;
        float s = g1[j] * rsqrtf(v1[j] + EPS_);
        fold1[tid] = make_float4(s * W1[2 * j], s * W1[2 * j + 1],
                                 fmaf(s, b1[j] - m1[j], be1[j]), 0.f);
    } else if (tid < H1_ + H2_) {                 // layer-2 BN fold
        int o = tid - H1_;
        int j = m * H2_ + o;
        float s = g2[j] * rsqrtf(v2[j] + EPS_);
        s2s[o] = s;
        c2s[o] = fmaf(s, b2p[j] - m2[j], be2[j]);
        w3s[o] = W3[j];
    }
    __syncthreads();

    const int lane = tid & 63;
    const int w    = tid >> 6;
    const int q    = lane >> 4;    // quad 0..3
    const int ln   = lane & 15;

    int i0, i1;
    pair_of_m(m, i0, i1);
    const float b3m = b3[m];
    const float* __restrict__ W2m = W2 + m * (H1_ * H2_);

    // ---- B fragments: bfr[n-tile u][k-step s], B[k=s*32+q*8+j][n=u*16+ln] ----
    bf16x8 bfr[2][2];
#pragma unroll
    for (int u = 0; u < 2; ++u)
#pragma unroll
        for (int s = 0; s < 2; ++s) {
            const float* p = W2m + (u * 16 + ln) * H1_ + s * 32 + q * 8;
            float4 f0 = *(const float4*)p;
            float4 f1 = *(const float4*)(p + 4);
            bf16x8 t;
            t[0] = f2bf(f0.x); t[1] = f2bf(f0.y); t[2] = f2bf(f0.z); t[3] = f2bf(f0.w);
            t[4] = f2bf(f1.x); t[5] = f2bf(f1.y); t[6] = f2bf(f1.z); t[7] = f2bf(f1.w);
            bfr[u][s] = t;
        }

    const int bbase = blockIdx.y * 256 + w * 64;

    // ---- per-tile x values ----
    float x0v[4], x1v[4];
#pragma unroll
    for (int t = 0; t < 4; ++t) {
        int b = bbase + t * 16 + ln;
        x0v[t] = x[b * NC_ + i0];
        x1v[t] = x[b * NC_ + i1];
    }

    // ---- A fragments (h1 in A-layout), one pass over this lane's k-set ----
    bf16x8 afr[4][2];
#pragma unroll
    for (int s = 0; s < 2; ++s)
#pragma unroll
        for (int j = 0; j < 8; ++j) {
            int k = s * 32 + q * 8 + j;
            float4 f = fold1[k];
#pragma unroll
            for (int t = 0; t < 4; ++t) {
                float h = fmaxf(fmaf(x0v[t], f.x, fmaf(x1v[t], f.y, f.z)), 0.f);
                afr[t][s][j] = f2bf(h);
            }
        }

    // ---- MFMA + epilogue per b-tile ----
#pragma unroll
    for (int t = 0; t < 4; ++t) {
        f32x4 acc0 = {0.f, 0.f, 0.f, 0.f};
        f32x4 acc1 = {0.f, 0.f, 0.f, 0.f};
        acc0 = __builtin_amdgcn_mfma_f32_16x16x32_bf16(afr[t][0], bfr[0][0], acc0, 0, 0, 0);
        acc0 = __builtin_amdgcn_mfma_f32_16x16x32_bf16(afr[t][1], bfr[0][1], acc0, 0, 0, 0);
        acc1 = __builtin_amdgcn_mfma_f32_16x16x32_bf16(afr[t][0], bfr[1][0], acc1, 0, 0, 0);
        acc1 = __builtin_amdgcn_mfma_f32_16x16x32_bf16(afr[t][1], bfr[1][1], acc1, 0, 0, 0);

        // C/D: lane holds (b = bbase+t*16+q*4+r, n = ln) and (n = 16+ln)
        float part[4];
#pragma unroll
        for (int r = 0; r < 4; ++r) {
            float h20 = fmaxf(fmaf(s2s[ln],      acc0[r], c2s[ln]),      0.f);
            float h21 = fmaxf(fmaf(s2s[16 + ln], acc1[r], c2s[16 + ln]), 0.f);
            part[r] = fmaf(h20, w3s[ln], h21 * w3s[16 + ln]);
        }
        // reduce over the 16 lanes of each quad (n-dimension)
#pragma unroll
        for (int mask = 1; mask < 16; mask <<= 1)
#pragma unroll
            for (int r = 0; r < 4; ++r)
                part[r] += __shfl_xor(part[r], mask, 64);
        // writer lanes: ln == r writes row q*4+r   (obuf m-major: coalesced-ish,
        // 1 KB contiguous region per block -> no write amplification)
#pragma unroll
        for (int r = 0; r < 4; ++r)
            if (ln == r)
                obuf[m * B_ + bbase + t * 16 + q * 4 + r] = part[r] + b3m;
    }
}

// ---------------- output projection ----------------
// grid = B_/64 = 32 blocks, block 256 = 64 b-lanes x 4 m-groups (1 wave each).
// m uniform per wave -> Wout reads scalarize; obuf reads coalesced (m-major).
__global__ __launch_bounds__(256) void k_out(
    const float* __restrict__ obuf, const float* __restrict__ Wout,
    const float* __restrict__ bout, float* __restrict__ out)
{
    __shared__ float red[256 * CLS_];
    const int tid = threadIdx.x;
    const int bl  = tid & 63;
    const int mg  = tid >> 6;                  // wave index = m-group
    const int b   = blockIdx.x * 64 + bl;

    float acc[CLS_];
#pragma unroll
    for (int c = 0; c < CLS_; ++c) acc[c] = 0.f;

#pragma unroll 4
    for (int m = mg; m < M_; m += 4) {
        float o = obuf[m * B_ + b];
#pragma unroll
        for (int c = 0; c < CLS_; ++c)
            acc[c] = fmaf(o, Wout[c * M_ + m], acc[c]);
    }
#pragma unroll
    for (int c = 0; c < CLS_; ++c) red[tid * CLS_ + c] = acc[c];
    __syncthreads();

    if (mg == 0) {
#pragma unroll
        for (int c = 0; c < CLS_; ++c) {
            float s = bout[c]
                    + red[(0 * 64 + bl) * CLS_ + c] + red[(1 * 64 + bl) * CLS_ + c]
                    + red[(2 * 64 + bl) * CLS_ + c] + red[(3 * 64 + bl) * CLS_ + c];
            out[b * CLS_ + c] = s;
        }
    }
}

// ---------------- workspace-free fallback (f32, known-good logic) ----------------
__global__ __launch_bounds__(256) void k_fused(
    const float* __restrict__ x,
    const float* __restrict__ W1, const float* __restrict__ b1,
    const float* __restrict__ g1, const float* __restrict__ be1,
    const float* __restrict__ m1, const float* __restrict__ v1,
    const float* __restrict__ W2, const float* __restrict__ b2p,
    const float* __restrict__ g2, const float* __restrict__ be2,
    const float* __restrict__ m2, const float* __restrict__ v2,
    const float* __restrict__ W3, const float* __restrict__ b3,
    const float* __restrict__ Wout, const float* __restrict__ bout,
    float* __restrict__ out)
{
    __shared__ float red[256 * CLS_];
    const int tid = threadIdx.x;
    const int bl  = tid & 7;
    const int mg  = tid >> 3;
    const int b   = blockIdx.x * 8 + bl;

    float acc[CLS_];
#pragma unroll
    for (int c = 0; c < CLS_; ++c) acc[c] = 0.f;

    for (int m = mg; m < M_; m += 32) {
        int i0, i1;
        pair_of_m(m, i0, i1);
        const float x0 = x[b * NC_ + i0];
        const float x1 = x[b * NC_ + i1];

        float h1[H1_];
#pragma unroll
        for (int o = 0; o < H1_; ++o) {
            int j = m * H1_ + o;
            float s = g1[j] * rsqrtf(v1[j] + EPS_);
            float pre = fmaf(x0, s * W1[2 * j],
                        fmaf(x1, s * W1[2 * j + 1],
                             fmaf(s, b1[j] - m1[j], be1[j])));
            h1[o] = fmaxf(pre, 0.f);
        }
        float acc3 = b3[m];
#pragma unroll 2
        for (int o = 0; o < H2_; ++o) {
            int j = m * H2_ + o;
            const float* __restrict__ r = W2 + j * H1_;
            float d = 0.f;
#pragma unroll
            for (int i = 0; i < H1_; ++i) d = fmaf(h1[i], r[i], d);
            float s = g2[j] * rsqrtf(v2[j] + EPS_);
            float h2 = fmaxf(fmaf(s, d + b2p[j] - m2[j], be2[j]), 0.f);
            acc3 = fmaf(h2, W3[j], acc3);
        }
#pragma unroll
        for (int c = 0; c < CLS_; ++c)
            acc[c] = fmaf(acc3, Wout[c * M_ + m], acc[c]);
    }

#pragma unroll
    for (int c = 0; c < CLS_; ++c) red[tid * CLS_ + c] = acc[c];
    __syncthreads();

    if (mg == 0) {
#pragma unroll
        for (int c = 0; c < CLS_; ++c) {
            float s = bout[c];
            for (int g = 0; g < 32; ++g)
                s += red[(g * 8 + bl) * CLS_ + c];
            out[b * CLS_ + c] = s;
        }
    }
}

// ---------------- launch ----------------
extern "C" void kernel_launch(void* const* d_in, const int* in_sizes, int n_in,
                              void* d_out, int out_size, void* d_ws, size_t ws_size,
                              hipStream_t stream)
{
    const float* x    = (const float*)d_in[0];
    // d_in[1] (pair_idx) unused: recomputed on device (dtype-immune).
    const float* W1   = (const float*)d_in[2];
    const float* b1   = (const float*)d_in[3];
    const float* g1   = (const float*)d_in[4];
    const float* be1  = (const float*)d_in[5];
    const float* m1   = (const float*)d_in[6];
    const float* v1   = (const float*)d_in[7];
    const float* W2   = (const float*)d_in[8];
    const float* b2p  = (const float*)d_in[9];
    const float* g2   = (const float*)d_in[10];
    const float* be2  = (const float*)d_in[11];
    const float* m2   = (const float*)d_in[12];
    const float* v2   = (const float*)d_in[13];
    const float* W3   = (const float*)d_in[14];
    const float* b3   = (const float*)d_in[15];
    const float* Wout = (const float*)d_in[16];
    const float* bout = (const float*)d_in[17];
    float* out  = (float*)d_out;
    float* obuf = (float*)d_ws;                 // [M_][B_] m-major, 4 MB

    if (ws_size >= (size_t)B_ * M_ * sizeof(float)) {
        k_mfma<<<dim3(M_, B_ / 256), 256, 0, stream>>>(
            x, W1, b1, g1, be1, m1, v1,
            W2, b2p, g2, be2, m2, v2, W3, b3, obuf);
        k_out<<<B_ / 64, 256, 0, stream>>>(obuf, Wout, bout, out);
    } else {
        k_fused<<<B_ / 8, 256, 0, stream>>>(
            x, W1, b1, g1, be1, m1, v1,
            W2, b2p, g2, be2, m2, v2, W3, b3, Wout, bout, out);
    }
}

// Round 6
// 121.559 us; speedup vs baseline: 1.4252x; 1.2462x over previous
//
#include <hip/hip_runtime.h>
#include <hip/hip_bf16.h>

// Problem constants
#define B_    2048
#define NC_   32
#define H1_   64
#define H2_   32
#define CLS_  10
#define M_    496
#define EPS_  1e-5f

typedef __attribute__((ext_vector_type(8))) short bf16x8;  // 8 bf16 (4 VGPRs)
typedef __attribute__((ext_vector_type(4))) float f32x4;   // MFMA C/D

union F8 { int4 i; bf16x8 h; };

// float -> bf16 (RNE) — used only in prep / non-PREP fallback paths
__device__ __forceinline__ short f2bf(float f) {
    unsigned u = __float_as_uint(f);
    u = (u + 0x7FFFu + ((u >> 16) & 1u)) >> 16;
    return (short)u;
}

// pack two floats' bf16(round-half-up) into one dword: low=e, high=o.
// ue+0x8000 then take high16 of each; single v_perm_b32 for the pack.
__device__ __forceinline__ unsigned pack_bf2(float e, float o) {
    unsigned ue = __float_as_uint(e) + 0x8000u;
    unsigned uo = __float_as_uint(o) + 0x8000u;
    return __builtin_amdgcn_perm(uo, ue, 0x07060302u);
}

// m -> (i0,i1): lexicographic pair from combinations(range(32),2).
__device__ __forceinline__ void pair_of_m(int m, int& i0, int& i1) {
    int a = 0, rem = m;
    while (rem >= (NC_ - 1 - a)) { rem -= (NC_ - 1 - a); ++a; }
    i0 = a; i1 = a + 1 + rem;
}

// ws layout (bytes)
#define OBUF_BYTES  ((size_t)M_ * B_ * 4)                 // 4,063,232
#define W2A_BYTES   ((size_t)M_ * 2 * 2 * 64 * 16)        // 2,031,616

// ---------------- one-time W2 -> bf16 MFMA-fragment prep ----------------
// frag index ((m*2+u)*2+s)*64 + lane ; lane=(q,ln): holds W2[m][u*16+ln][s*32+q*8 .. +7]
__global__ __launch_bounds__(256) void k_prep(
    const float* __restrict__ W2, int4* __restrict__ W2a)
{
    int t = blockIdx.x * 256 + threadIdx.x;      // 496*256 threads exactly
    int lane = t & 63, s = (t >> 6) & 1, u = (t >> 7) & 1, m = t >> 8;
    int q = lane >> 4, ln = lane & 15;
    const float* p = W2 + m * (H2_ * H1_) + (u * 16 + ln) * H1_ + s * 32 + q * 8;
    float4 f0 = *(const float4*)p;
    float4 f1 = *(const float4*)(p + 4);
    int4 d;
    d.x = ((unsigned)(unsigned short)f2bf(f0.x)) | ((unsigned)(unsigned short)f2bf(f0.y) << 16);
    d.y = ((unsigned)(unsigned short)f2bf(f0.z)) | ((unsigned)(unsigned short)f2bf(f0.w) << 16);
    d.z = ((unsigned)(unsigned short)f2bf(f1.x)) | ((unsigned)(unsigned short)f2bf(f1.y) << 16);
    d.w = ((unsigned)(unsigned short)f2bf(f1.z)) | ((unsigned)(unsigned short)f2bf(f1.w) << 16);
    W2a[t] = d;
}

// ---------------- main kernel ----------------
// grid = (M_, 8), block = 256 (4 waves). Wave w: 4 b-tiles of 16 (64 batches).
// MFMA roles: A = W2 [n x k], B = h1 [k x b]  ->  D[n][b] (n in quad/reg dim).
template <bool PREP>
__global__ __launch_bounds__(256) void k_main2(
    const float* __restrict__ x,
    const float* __restrict__ W1, const float* __restrict__ b1,
    const float* __restrict__ g1, const float* __restrict__ be1,
    const float* __restrict__ m1, const float* __restrict__ v1,
    const float* __restrict__ W2, const int4* __restrict__ W2a,
    const float* __restrict__ b2p,
    const float* __restrict__ g2, const float* __restrict__ be2,
    const float* __restrict__ m2, const float* __restrict__ v2,
    const float* __restrict__ W3, const float* __restrict__ b3,
    float* __restrict__ obuf)
{
    __shared__ float w1aS[H1_], w1bS[H1_], c1S[H1_];
    __shared__ float s2S[H2_], c2S[H2_], w3S[H2_];
    __shared__ float xs0[256], xs1[256];

    const int m   = blockIdx.x;
    const int tid = threadIdx.x;

    int i0, i1;
    pair_of_m(m, i0, i1);

    if (tid < H1_) {                               // layer-1 BN fold
        int j = m * H1_ + tid;
        float s = g1[j] * rsqrtf(v1[j] + EPS_);
        w1aS[tid] = s * W1[2 * j];
        w1bS[tid] = s * W1[2 * j + 1];
        c1S[tid]  = fmaf(s, b1[j] - m1[j], be1[j]);
    } else if (tid < H1_ + H2_) {                  // layer-2 BN fold
        int o = tid - H1_;
        int j = m * H2_ + o;
        float s = g2[j] * rsqrtf(v2[j] + EPS_);
        s2S[o] = s;
        c2S[o] = fmaf(s, b2p[j] - m2[j], be2[j]);
        w3S[o] = W3[j];
    }
    {   // stage x columns for this block's 256 batches
        int b = blockIdx.y * 256 + tid;
        xs0[tid] = x[b * NC_ + i0];
        xs1[tid] = x[b * NC_ + i1];
    }
    __syncthreads();

    const int lane = tid & 63;
    const int w    = tid >> 6;
    const int q    = lane >> 4;
    const int ln   = lane & 15;
    const int wbase = w * 64;                      // batch offset within block
    const float b3m = b3[m];

    // ---- W2 fragments (A operand): wfr[u][s] ----
    F8 wfr[2][2];
    if (PREP) {
        const int4* p = W2a + (m * 4) * 64 + lane;
#pragma unroll
        for (int u = 0; u < 2; ++u)
#pragma unroll
            for (int s = 0; s < 2; ++s)
                wfr[u][s].i = p[(u * 2 + s) * 64];
    } else {
        const float* W2m = W2 + m * (H2_ * H1_);
#pragma unroll
        for (int u = 0; u < 2; ++u)
#pragma unroll
            for (int s = 0; s < 2; ++s) {
                const float* p = W2m + (u * 16 + ln) * H1_ + s * 32 + q * 8;
                float4 f0 = *(const float4*)p;
                float4 f1 = *(const float4*)(p + 4);
                int4 d;
                d.x = ((unsigned)(unsigned short)f2bf(f0.x)) | ((unsigned)(unsigned short)f2bf(f0.y) << 16);
                d.y = ((unsigned)(unsigned short)f2bf(f0.z)) | ((unsigned)(unsigned short)f2bf(f0.w) << 16);
                d.z = ((unsigned)(unsigned short)f2bf(f1.x)) | ((unsigned)(unsigned short)f2bf(f1.y) << 16);
                d.w = ((unsigned)(unsigned short)f2bf(f1.z)) | ((unsigned)(unsigned short)f2bf(f1.w) << 16);
                wfr[u][s].i = d;
            }
    }

    // ---- per-tile x values (from LDS; conflict-free 16-distinct/4-bcast) ----
    float x0v[4], x1v[4];
#pragma unroll
    for (int t = 0; t < 4; ++t) {
        x0v[t] = xs0[wbase + t * 16 + ln];
        x1v[t] = xs1[wbase + t * 16 + ln];
    }

    // ---- epilogue constants (per-lane n-slots, reused across tiles) ----
    float s2a0[4], c2a0[4], w3a0[4], s2a1[4], c2a1[4], w3a1[4];
#pragma unroll
    for (int r = 0; r < 4; ++r) {
        int n0 = q * 4 + r, n1 = 16 + n0;
        s2a0[r] = s2S[n0]; c2a0[r] = c2S[n0]; w3a0[r] = w3S[n0];
        s2a1[r] = s2S[n1]; c2a1[r] = c2S[n1]; w3a1[r] = w3S[n1];
    }

    // ---- h1 fragments (B operand): hfr[t][s], element j = k-offset ----
    // k = s*32 + q*8 + j ; LDS banks 8q+j -> conflict-free.
    F8 hfr[4][2];
#pragma unroll
    for (int s = 0; s < 2; ++s)
#pragma unroll
        for (int jp = 0; jp < 4; ++jp) {
            int ke = s * 32 + q * 8 + 2 * jp;
            float wae = w1aS[ke],     wbe = w1bS[ke],     ce = c1S[ke];
            float wao = w1aS[ke + 1], wbo = w1bS[ke + 1], co = c1S[ke + 1];
            unsigned dw[4];
#pragma unroll
            for (int t = 0; t < 4; ++t) {
                float he = fmaxf(fmaf(x0v[t], wae, fmaf(x1v[t], wbe, ce)), 0.f);
                float ho = fmaxf(fmaf(x0v[t], wao, fmaf(x1v[t], wbo, co)), 0.f);
                dw[t] = pack_bf2(he, ho);
            }
            hfr[0][s].i[jp] = dw[0];  hfr[1][s].i[jp] = dw[1];
            hfr[2][s].i[jp] = dw[2];  hfr[3][s].i[jp] = dw[3];
        }

    // ---- MFMA + epilogue ----
    float ot[4];
#pragma unroll
    for (int t = 0; t < 4; ++t) {
        f32x4 acc0 = {0.f, 0.f, 0.f, 0.f};
        f32x4 acc1 = {0.f, 0.f, 0.f, 0.f};
        acc0 = __builtin_amdgcn_mfma_f32_16x16x32_bf16(wfr[0][0].h, hfr[t][0].h, acc0, 0, 0, 0);
        acc0 = __builtin_amdgcn_mfma_f32_16x16x32_bf16(wfr[0][1].h, hfr[t][1].h, acc0, 0, 0, 0);
        acc1 = __builtin_amdgcn_mfma_f32_16x16x32_bf16(wfr[1][0].h, hfr[t][0].h, acc1, 0, 0, 0);
        acc1 = __builtin_amdgcn_mfma_f32_16x16x32_bf16(wfr[1][1].h, hfr[t][1].h, acc1, 0, 0, 0);

        // lane holds S[n=q*4+r (+16)][b=tbase+ln]; reduce n in-register,
        // then 2 butterfly steps across quads.
        float part = 0.f;
#pragma unroll
        for (int r = 0; r < 4; ++r) {
            float h20 = fmaxf(fmaf(s2a0[r], acc0[r], c2a0[r]), 0.f);
            float h21 = fmaxf(fmaf(s2a1[r], acc1[r], c2a1[r]), 0.f);
            part = fmaf(h20, w3a0[r], fmaf(h21, w3a1[r], part));
        }
        part += __shfl_xor(part, 16, 64);
        part += __shfl_xor(part, 32, 64);
        ot[t] = part;
    }

    // quad q stores tile t=q  ->  one coalesced 256B store per wave
    float o = (q == 0) ? ot[0] : (q == 1) ? ot[1] : (q == 2) ? ot[2] : ot[3];
    obuf[m * B_ + blockIdx.y * 256 + wbase + lane] = o + b3m;
}

// ---------------- output projection ----------------
// grid = B_/32 = 64 blocks, block 256 = 32 b-lanes x 8 m-groups.
__global__ __launch_bounds__(256) void k_out(
    const float* __restrict__ obuf, const float* __restrict__ Wout,
    const float* __restrict__ bout, float* __restrict__ out)
{
    __shared__ float red[256 * CLS_];
    const int tid = threadIdx.x;
    const int bl  = tid & 31;
    const int mg  = tid >> 5;
    const int b   = blockIdx.x * 32 + bl;

    float acc[CLS_];
#pragma unroll
    for (int c = 0; c < CLS_; ++c) acc[c] = 0.f;

#pragma unroll 4
    for (int m = mg; m < M_; m += 8) {
        float o = obuf[m * B_ + b];
#pragma unroll
        for (int c = 0; c < CLS_; ++c)
            acc[c] = fmaf(o, Wout[c * M_ + m], acc[c]);
    }
#pragma unroll
    for (int c = 0; c < CLS_; ++c) red[tid * CLS_ + c] = acc[c];
    __syncthreads();

    if (mg == 0) {
#pragma unroll
        for (int c = 0; c < CLS_; ++c) {
            float s = bout[c];
#pragma unroll
            for (int g = 0; g < 8; ++g)
                s += red[(g * 32 + bl) * CLS_ + c];
            out[b * CLS_ + c] = s;
        }
    }
}

// ---------------- workspace-free fallback (known-good) ----------------
__global__ __launch_bounds__(256) void k_fused(
    const float* __restrict__ x,
    const float* __restrict__ W1, const float* __restrict__ b1,
    const float* __restrict__ g1, const float* __restrict__ be1,
    const float* __restrict__ m1, const float* __restrict__ v1,
    const float* __restrict__ W2, const float* __restrict__ b2p,
    const float* __restrict__ g2, const float* __restrict__ be2,
    const float* __restrict__ m2, const float* __restrict__ v2,
    const float* __restrict__ W3, const float* __restrict__ b3,
    const float* __restrict__ Wout, const float* __restrict__ bout,
    float* __restrict__ out)
{
    __shared__ float red[256 * CLS_];
    const int tid = threadIdx.x;
    const int bl  = tid & 7;
    const int mg  = tid >> 3;
    const int b   = blockIdx.x * 8 + bl;

    float acc[CLS_];
#pragma unroll
    for (int c = 0; c < CLS_; ++c) acc[c] = 0.f;

    for (int m = mg; m < M_; m += 32) {
        int i0, i1;
        pair_of_m(m, i0, i1);
        const float x0 = x[b * NC_ + i0];
        const float x1 = x[b * NC_ + i1];

        float h1[H1_];
#pragma unroll
        for (int o = 0; o < H1_; ++o) {
            int j = m * H1_ + o;
            float s = g1[j] * rsqrtf(v1[j] + EPS_);
            float pre = fmaf(x0, s * W1[2 * j],
                        fmaf(x1, s * W1[2 * j + 1],
                             fmaf(s, b1[j] - m1[j], be1[j])));
            h1[o] = fmaxf(pre, 0.f);
        }
        float acc3 = b3[m];
#pragma unroll 2
        for (int o = 0; o < H2_; ++o) {
            int j = m * H2_ + o;
            const float* __restrict__ r = W2 + j * H1_;
            float d = 0.f;
#pragma unroll
            for (int i = 0; i < H1_; ++i) d = fmaf(h1[i], r[i], d);
            float s = g2[j] * rsqrtf(v2[j] + EPS_);
            float h2 = fmaxf(fmaf(s, d + b2p[j] - m2[j], be2[j]), 0.f);
            acc3 = fmaf(h2, W3[j], acc3);
        }
#pragma unroll
        for (int c = 0; c < CLS_; ++c)
            acc[c] = fmaf(acc3, Wout[c * M_ + m], acc[c]);
    }

#pragma unroll
    for (int c = 0; c < CLS_; ++c) red[tid * CLS_ + c] = acc[c];
    __syncthreads();

    if (mg == 0) {
#pragma unroll
        for (int c = 0; c < CLS_; ++c) {
            float s = bout[c];
            for (int g = 0; g < 32; ++g)
                s += red[(g * 8 + bl) * CLS_ + c];
            out[b * CLS_ + c] = s;
        }
    }
}

// ---------------- launch ----------------
extern "C" void kernel_launch(void* const* d_in, const int* in_sizes, int n_in,
                              void* d_out, int out_size, void* d_ws, size_t ws_size,
                              hipStream_t stream)
{
    const float* x    = (const float*)d_in[0];
    // d_in[1] (pair_idx) unused: recomputed on device (dtype-immune).
    const float* W1   = (const float*)d_in[2];
    const float* b1   = (const float*)d_in[3];
    const float* g1   = (const float*)d_in[4];
    const float* be1  = (const float*)d_in[5];
    const float* m1   = (const float*)d_in[6];
    const float* v1   = (const float*)d_in[7];
    const float* W2   = (const float*)d_in[8];
    const float* b2p  = (const float*)d_in[9];
    const float* g2   = (const float*)d_in[10];
    const float* be2  = (const float*)d_in[11];
    const float* m2   = (const float*)d_in[12];
    const float* v2   = (const float*)d_in[13];
    const float* W3   = (const float*)d_in[14];
    const float* b3   = (const float*)d_in[15];
    const float* Wout = (const float*)d_in[16];
    const float* bout = (const float*)d_in[17];
    float* out  = (float*)d_out;
    float* obuf = (float*)d_ws;
    int4*  W2a  = (int4*)((char*)d_ws + OBUF_BYTES);

    if (ws_size >= OBUF_BYTES + W2A_BYTES) {
        k_prep<<<M_, 256, 0, stream>>>(W2, W2a);
        k_main2<true><<<dim3(M_, B_ / 256), 256, 0, stream>>>(
            x, W1, b1, g1, be1, m1, v1, W2, W2a,
            b2p, g2, be2, m2, v2, W3, b3, obuf);
        k_out<<<B_ / 32, 256, 0, stream>>>(obuf, Wout, bout, out);
    } else if (ws_size >= OBUF_BYTES) {
        k_main2<false><<<dim3(M_, B_ / 256), 256, 0, stream>>>(
            x, W1, b1, g1, be1, m1, v1, W2, (const int4*)nullptr,
            b2p, g2, be2, m2, v2, W3, b3, obuf);
        k_out<<<B_ / 32, 256, 0, stream>>>(obuf, Wout, bout, out);
    } else {
        k_fused<<<B_ / 8, 256, 0, stream>>>(
            x, W1, b1, g1, be1, m1, v1,
            W2, b2p, g2, be2, m2, v2, W3, b3, Wout, bout, out);
    }
}

// Round 7
// 116.459 us; speedup vs baseline: 1.4876x; 1.0438x over previous
//
#include <hip/hip_runtime.h>
#include <hip/hip_bf16.h>

// Problem constants
#define B_    2048
#define NC_   32
#define H1_   64
#define H2_   32
#define CLS_  10
#define M_    496
#define EPS_  1e-5f

typedef __attribute__((ext_vector_type(8))) short bf16x8;  // 8 bf16 (4 VGPRs)
typedef __attribute__((ext_vector_type(4))) float f32x4;   // MFMA C/D

union F8 { int4 i; bf16x8 h; };

// float -> bf16 (RNE)
__device__ __forceinline__ short f2bf(float f) {
    unsigned u = __float_as_uint(f);
    u = (u + 0x7FFFu + ((u >> 16) & 1u)) >> 16;
    return (short)u;
}

// pack two floats' bf16(round-half-up) into one dword: low=e, high=o.
__device__ __forceinline__ unsigned pack_bf2(float e, float o) {
    unsigned ue = __float_as_uint(e) + 0x8000u;
    unsigned uo = __float_as_uint(o) + 0x8000u;
    return __builtin_amdgcn_perm(uo, ue, 0x07060302u);
}

// m -> (i0,i1): lexicographic pair from combinations(range(32),2).
__device__ __forceinline__ void pair_of_m(int m, int& i0, int& i1) {
    int a = 0, rem = m;
    while (rem >= (NC_ - 1 - a)) { rem -= (NC_ - 1 - a); ++a; }
    i0 = a; i1 = a + 1 + rem;
}

// ws layout (bytes)
#define OBUF_BYTES  ((size_t)M_ * B_ * 4)                  // 4,063,232
#define W2A_BYTES   ((size_t)M_ * 2 * 2 * 64 * 16)         // 2,031,616
#define NCHUNK 16
#define PBUF_BYTES  ((size_t)NCHUNK * B_ * CLS_ * 4)       // 1,310,720

// ---------------- one-time W2 -> bf16 MFMA-fragment prep ----------------
__global__ __launch_bounds__(256) void k_prep(
    const float* __restrict__ W2, int4* __restrict__ W2a)
{
    int t = blockIdx.x * 256 + threadIdx.x;      // 496*256 threads exactly
    int lane = t & 63, s = (t >> 6) & 1, u = (t >> 7) & 1, m = t >> 8;
    int q = lane >> 4, ln = lane & 15;
    const float* p = W2 + m * (H2_ * H1_) + (u * 16 + ln) * H1_ + s * 32 + q * 8;
    float4 f0 = *(const float4*)p;
    float4 f1 = *(const float4*)(p + 4);
    int4 d;
    d.x = ((unsigned)(unsigned short)f2bf(f0.x)) | ((unsigned)(unsigned short)f2bf(f0.y) << 16);
    d.y = ((unsigned)(unsigned short)f2bf(f0.z)) | ((unsigned)(unsigned short)f2bf(f0.w) << 16);
    d.z = ((unsigned)(unsigned short)f2bf(f1.x)) | ((unsigned)(unsigned short)f2bf(f1.y) << 16);
    d.w = ((unsigned)(unsigned short)f2bf(f1.z)) | ((unsigned)(unsigned short)f2bf(f1.w) << 16);
    W2a[t] = d;
}

// ---------------- main kernel ----------------
// grid = (M_, 4), block = 256 (4 waves). Wave w: 128 batches = 2 halves x 4 tiles x 16.
// MFMA roles: A = W2 [n x k], B = h1 [k x b]  ->  D[n][b].
template <bool PREP>
__global__ __launch_bounds__(256) void k_main3(
    const float* __restrict__ x,
    const float* __restrict__ W1, const float* __restrict__ b1,
    const float* __restrict__ g1, const float* __restrict__ be1,
    const float* __restrict__ m1, const float* __restrict__ v1,
    const float* __restrict__ W2, const int4* __restrict__ W2a,
    const float* __restrict__ b2p,
    const float* __restrict__ g2, const float* __restrict__ be2,
    const float* __restrict__ m2, const float* __restrict__ v2,
    const float* __restrict__ W3, const float* __restrict__ b3,
    float* __restrict__ obuf)
{
    __shared__ float w1aS[H1_], w1bS[H1_], c1S[H1_];
    __shared__ float s2S[H2_], c2S[H2_], w3S[H2_];
    __shared__ float xs0[512], xs1[512];

    const int m   = blockIdx.x;
    const int tid = threadIdx.x;

    int i0, i1;
    pair_of_m(m, i0, i1);

    if (tid < H1_) {                               // layer-1 BN fold
        int j = m * H1_ + tid;
        float s = g1[j] * rsqrtf(v1[j] + EPS_);
        w1aS[tid] = s * W1[2 * j];
        w1bS[tid] = s * W1[2 * j + 1];
        c1S[tid]  = fmaf(s, b1[j] - m1[j], be1[j]);
    } else if (tid < H1_ + H2_) {                  // layer-2 BN fold
        int o = tid - H1_;
        int j = m * H2_ + o;
        float s = g2[j] * rsqrtf(v2[j] + EPS_);
        s2S[o] = s;
        c2S[o] = fmaf(s, b2p[j] - m2[j], be2[j]);
        w3S[o] = W3[j];
    }
    {   // stage x columns for this block's 512 batches
        int bb = blockIdx.y * 512;
        xs0[tid]       = x[(bb + tid) * NC_ + i0];
        xs1[tid]       = x[(bb + tid) * NC_ + i1];
        xs0[256 + tid] = x[(bb + 256 + tid) * NC_ + i0];
        xs1[256 + tid] = x[(bb + 256 + tid) * NC_ + i1];
    }
    __syncthreads();

    const int lane = tid & 63;
    const int w    = tid >> 6;
    const int q    = lane >> 4;
    const int ln   = lane & 15;
    const int wbase = w * 128;                     // batch offset within block
    const float b3m = b3[m];

    // ---- W2 fragments (A operand): wfr[u][s] ----
    F8 wfr[2][2];
    if (PREP) {
        const int4* p = W2a + (m * 4) * 64 + lane;
#pragma unroll
        for (int u = 0; u < 2; ++u)
#pragma unroll
            for (int s = 0; s < 2; ++s)
                wfr[u][s].i = p[(u * 2 + s) * 64];
    } else {
        const float* W2m = W2 + m * (H2_ * H1_);
#pragma unroll
        for (int u = 0; u < 2; ++u)
#pragma unroll
            for (int s = 0; s < 2; ++s) {
                const float* p = W2m + (u * 16 + ln) * H1_ + s * 32 + q * 8;
                float4 f0 = *(const float4*)p;
                float4 f1 = *(const float4*)(p + 4);
                int4 d;
                d.x = ((unsigned)(unsigned short)f2bf(f0.x)) | ((unsigned)(unsigned short)f2bf(f0.y) << 16);
                d.y = ((unsigned)(unsigned short)f2bf(f0.z)) | ((unsigned)(unsigned short)f2bf(f0.w) << 16);
                d.z = ((unsigned)(unsigned short)f2bf(f1.x)) | ((unsigned)(unsigned short)f2bf(f1.y) << 16);
                d.w = ((unsigned)(unsigned short)f2bf(f1.z)) | ((unsigned)(unsigned short)f2bf(f1.w) << 16);
                wfr[u][s].i = d;
            }
    }

    // ---- epilogue constants (per-lane n-slots) ----
    float s2a0[4], c2a0[4], w3a0[4], s2a1[4], c2a1[4], w3a1[4];
#pragma unroll
    for (int r = 0; r < 4; ++r) {
        int n0 = q * 4 + r, n1 = 16 + n0;
        s2a0[r] = s2S[n0]; c2a0[r] = c2S[n0]; w3a0[r] = w3S[n0];
        s2a1[r] = s2S[n1]; c2a1[r] = c2S[n1]; w3a1[r] = w3S[n1];
    }

#pragma unroll
    for (int h = 0; h < 2; ++h) {
        const int hbase = wbase + h * 64;

        float x0v[4], x1v[4];
#pragma unroll
        for (int t = 0; t < 4; ++t) {
            x0v[t] = xs0[hbase + t * 16 + ln];
            x1v[t] = xs1[hbase + t * 16 + ln];
        }

        // ---- h1 fragments (B operand): k = s*32 + q*8 + j ----
        F8 hfr[4][2];
#pragma unroll
        for (int s = 0; s < 2; ++s)
#pragma unroll
            for (int jp = 0; jp < 4; ++jp) {
                int ke = s * 32 + q * 8 + 2 * jp;
                float wae = w1aS[ke],     wbe = w1bS[ke],     ce = c1S[ke];
                float wao = w1aS[ke + 1], wbo = w1bS[ke + 1], co = c1S[ke + 1];
                unsigned dw[4];
#pragma unroll
                for (int t = 0; t < 4; ++t) {
                    float he = fmaxf(fmaf(x0v[t], wae, fmaf(x1v[t], wbe, ce)), 0.f);
                    float ho = fmaxf(fmaf(x0v[t], wao, fmaf(x1v[t], wbo, co)), 0.f);
                    dw[t] = pack_bf2(he, ho);
                }
                hfr[0][s].i[jp] = dw[0];  hfr[1][s].i[jp] = dw[1];
                hfr[2][s].i[jp] = dw[2];  hfr[3][s].i[jp] = dw[3];
            }

        // ---- MFMA + epilogue ----
        float ot[4];
#pragma unroll
        for (int t = 0; t < 4; ++t) {
            f32x4 acc0 = {0.f, 0.f, 0.f, 0.f};
            f32x4 acc1 = {0.f, 0.f, 0.f, 0.f};
            acc0 = __builtin_amdgcn_mfma_f32_16x16x32_bf16(wfr[0][0].h, hfr[t][0].h, acc0, 0, 0, 0);
            acc0 = __builtin_amdgcn_mfma_f32_16x16x32_bf16(wfr[0][1].h, hfr[t][1].h, acc0, 0, 0, 0);
            acc1 = __builtin_amdgcn_mfma_f32_16x16x32_bf16(wfr[1][0].h, hfr[t][0].h, acc1, 0, 0, 0);
            acc1 = __builtin_amdgcn_mfma_f32_16x16x32_bf16(wfr[1][1].h, hfr[t][1].h, acc1, 0, 0, 0);

            float part = 0.f;
#pragma unroll
            for (int r = 0; r < 4; ++r) {
                float h20 = fmaxf(fmaf(s2a0[r], acc0[r], c2a0[r]), 0.f);
                float h21 = fmaxf(fmaf(s2a1[r], acc1[r], c2a1[r]), 0.f);
                part = fmaf(h20, w3a0[r], fmaf(h21, w3a1[r], part));
            }
            part += __shfl_xor(part, 16, 64);
            part += __shfl_xor(part, 32, 64);
            ot[t] = part;
        }

        // quad q stores tile t=q -> one coalesced 256B store per wave per half
        float o = (q == 0) ? ot[0] : (q == 1) ? ot[1] : (q == 2) ? ot[2] : ot[3];
        obuf[m * B_ + blockIdx.y * 512 + hbase + lane] = o + b3m;
    }
}

// ---------------- output projection, stage 1: partials ----------------
// grid = (32 b-tiles, 16 m-chunks of 31). block 256 = 64 b-lanes x 4 m-groups.
__global__ __launch_bounds__(256) void k_outp(
    const float* __restrict__ obuf, const float* __restrict__ Wout,
    float* __restrict__ pbuf)
{
    __shared__ float red[256 * CLS_];
    const int tid = threadIdx.x;
    const int bl  = tid & 63;
    const int mg  = tid >> 6;
    const int b   = blockIdx.x * 64 + bl;
    const int mb  = blockIdx.y * 31;

    float acc[CLS_];
#pragma unroll
    for (int c = 0; c < CLS_; ++c) acc[c] = 0.f;

    for (int i = mg; i < 31; i += 4) {
        int m = mb + i;
        float o = obuf[m * B_ + b];
#pragma unroll
        for (int c = 0; c < CLS_; ++c)
            acc[c] = fmaf(o, Wout[c * M_ + m], acc[c]);
    }
#pragma unroll
    for (int c = 0; c < CLS_; ++c) red[tid * CLS_ + c] = acc[c];
    __syncthreads();

    if (mg == 0) {
#pragma unroll
        for (int c = 0; c < CLS_; ++c) {
            float s = red[(0 * 64 + bl) * CLS_ + c] + red[(1 * 64 + bl) * CLS_ + c]
                    + red[(2 * 64 + bl) * CLS_ + c] + red[(3 * 64 + bl) * CLS_ + c];
            pbuf[(blockIdx.y * B_ + b) * CLS_ + c] = s;
        }
    }
}

// ---------------- output projection, stage 2: finish ----------------
__global__ __launch_bounds__(256) void k_fin(
    const float* __restrict__ pbuf, const float* __restrict__ bout,
    float* __restrict__ out)
{
    int t = blockIdx.x * 256 + threadIdx.x;       // B_*CLS_ = 20480 exactly
    int c = t % CLS_;
    float s = bout[c];
#pragma unroll
    for (int ch = 0; ch < NCHUNK; ++ch)
        s += pbuf[ch * (B_ * CLS_) + t];
    out[t] = s;
}

// ---------------- mid-tier single-stage k_out (obuf-only ws) ----------------
__global__ __launch_bounds__(256) void k_out1(
    const float* __restrict__ obuf, const float* __restrict__ Wout,
    const float* __restrict__ bout, float* __restrict__ out)
{
    __shared__ float red[256 * CLS_];
    const int tid = threadIdx.x;
    const int bl  = tid & 31;
    const int mg  = tid >> 5;
    const int b   = blockIdx.x * 32 + bl;

    float acc[CLS_];
#pragma unroll
    for (int c = 0; c < CLS_; ++c) acc[c] = 0.f;
#pragma unroll 4
    for (int m = mg; m < M_; m += 8) {
        float o = obuf[m * B_ + b];
#pragma unroll
        for (int c = 0; c < CLS_; ++c)
            acc[c] = fmaf(o, Wout[c * M_ + m], acc[c]);
    }
#pragma unroll
    for (int c = 0; c < CLS_; ++c) red[tid * CLS_ + c] = acc[c];
    __syncthreads();
    if (mg == 0) {
#pragma unroll
        for (int c = 0; c < CLS_; ++c) {
            float s = bout[c];
#pragma unroll
            for (int g = 0; g < 8; ++g)
                s += red[(g * 32 + bl) * CLS_ + c];
            out[b * CLS_ + c] = s;
        }
    }
}

// ---------------- workspace-free fallback (known-good) ----------------
__global__ __launch_bounds__(256) void k_fused(
    const float* __restrict__ x,
    const float* __restrict__ W1, const float* __restrict__ b1,
    const float* __restrict__ g1, const float* __restrict__ be1,
    const float* __restrict__ m1, const float* __restrict__ v1,
    const float* __restrict__ W2, const float* __restrict__ b2p,
    const float* __restrict__ g2, const float* __restrict__ be2,
    const float* __restrict__ m2, const float* __restrict__ v2,
    const float* __restrict__ W3, const float* __restrict__ b3,
    const float* __restrict__ Wout, const float* __restrict__ bout,
    float* __restrict__ out)
{
    __shared__ float red[256 * CLS_];
    const int tid = threadIdx.x;
    const int bl  = tid & 7;
    const int mg  = tid >> 3;
    const int b   = blockIdx.x * 8 + bl;

    float acc[CLS_];
#pragma unroll
    for (int c = 0; c < CLS_; ++c) acc[c] = 0.f;

    for (int m = mg; m < M_; m += 32) {
        int i0, i1;
        pair_of_m(m, i0, i1);
        const float x0 = x[b * NC_ + i0];
        const float x1 = x[b * NC_ + i1];
        float h1[H1_];
#pragma unroll
        for (int o = 0; o < H1_; ++o) {
            int j = m * H1_ + o;
            float s = g1[j] * rsqrtf(v1[j] + EPS_);
            float pre = fmaf(x0, s * W1[2 * j],
                        fmaf(x1, s * W1[2 * j + 1],
                             fmaf(s, b1[j] - m1[j], be1[j])));
            h1[o] = fmaxf(pre, 0.f);
        }
        float acc3 = b3[m];
#pragma unroll 2
        for (int o = 0; o < H2_; ++o) {
            int j = m * H2_ + o;
            const float* __restrict__ r = W2 + j * H1_;
            float d = 0.f;
#pragma unroll
            for (int i = 0; i < H1_; ++i) d = fmaf(h1[i], r[i], d);
            float s = g2[j] * rsqrtf(v2[j] + EPS_);
            float h2 = fmaxf(fmaf(s, d + b2p[j] - m2[j], be2[j]), 0.f);
            acc3 = fmaf(h2, W3[j], acc3);
        }
#pragma unroll
        for (int c = 0; c < CLS_; ++c)
            acc[c] = fmaf(acc3, Wout[c * M_ + m], acc[c]);
    }

#pragma unroll
    for (int c = 0; c < CLS_; ++c) red[tid * CLS_ + c] = acc[c];
    __syncthreads();
    if (mg == 0) {
#pragma unroll
        for (int c = 0; c < CLS_; ++c) {
            float s = bout[c];
            for (int g = 0; g < 32; ++g)
                s += red[(g * 8 + bl) * CLS_ + c];
            out[b * CLS_ + c] = s;
        }
    }
}

// ---------------- launch ----------------
extern "C" void kernel_launch(void* const* d_in, const int* in_sizes, int n_in,
                              void* d_out, int out_size, void* d_ws, size_t ws_size,
                              hipStream_t stream)
{
    const float* x    = (const float*)d_in[0];
    // d_in[1] (pair_idx) unused: recomputed on device (dtype-immune).
    const float* W1   = (const float*)d_in[2];
    const float* b1   = (const float*)d_in[3];
    const float* g1   = (const float*)d_in[4];
    const float* be1  = (const float*)d_in[5];
    const float* m1   = (const float*)d_in[6];
    const float* v1   = (const float*)d_in[7];
    const float* W2   = (const float*)d_in[8];
    const float* b2p  = (const float*)d_in[9];
    const float* g2   = (const float*)d_in[10];
    const float* be2  = (const float*)d_in[11];
    const float* m2   = (const float*)d_in[12];
    const float* v2   = (const float*)d_in[13];
    const float* W3   = (const float*)d_in[14];
    const float* b3   = (const float*)d_in[15];
    const float* Wout = (const float*)d_in[16];
    const float* bout = (const float*)d_in[17];
    float* out  = (float*)d_out;
    float* obuf = (float*)d_ws;
    int4*  W2a  = (int4*)((char*)d_ws + OBUF_BYTES);
    float* pbuf = (float*)((char*)d_ws + OBUF_BYTES + W2A_BYTES);

    if (ws_size >= OBUF_BYTES + W2A_BYTES + PBUF_BYTES) {
        k_prep<<<M_, 256, 0, stream>>>(W2, W2a);
        k_main3<true><<<dim3(M_, B_ / 512), 256, 0, stream>>>(
            x, W1, b1, g1, be1, m1, v1, W2, W2a,
            b2p, g2, be2, m2, v2, W3, b3, obuf);
        k_outp<<<dim3(B_ / 64, NCHUNK), 256, 0, stream>>>(obuf, Wout, pbuf);
        k_fin<<<(B_ * CLS_) / 256, 256, 0, stream>>>(pbuf, bout, out);
    } else if (ws_size >= OBUF_BYTES) {
        k_main3<false><<<dim3(M_, B_ / 512), 256, 0, stream>>>(
            x, W1, b1, g1, be1, m1, v1, W2, (const int4*)nullptr,
            b2p, g2, be2, m2, v2, W3, b3, obuf);
        k_out1<<<B_ / 32, 256, 0, stream>>>(obuf, Wout, bout, out);
    } else {
        k_fused<<<B_ / 8, 256, 0, stream>>>(
            x, W1, b1, g1, be1, m1, v1,
            W2, b2p, g2, be2, m2, v2, W3, b3, Wout, bout, out);
    }
}